// Round 1
// baseline (579.608 us; speedup 1.0000x reference)
//
#include <hip/hip_runtime.h>

// ---------------------------------------------------------------------------
// GCN 2-layer forward on MI355X.
// Strategy: CSR build via counting sort (int atomics only), then
//   hs = (X @ W) * dinv[row]   (LDS-tiled fp32 GEMM, 4x4 register tile)
//   out[i] = act(dinv[i] * (sum_{j->i} hs[j] + hs[i]) + b)   (gather, no atomics)
// ---------------------------------------------------------------------------

#define KDIM 128

// ---- CSR build ------------------------------------------------------------

__global__ void hist_kernel(const int* __restrict__ dst, int* __restrict__ hist, int E) {
    int i = blockIdx.x * blockDim.x + threadIdx.x;
    if (i < E) atomicAdd(&hist[dst[i]], 1);
}

// per-block (1024 elems) exclusive scan; block totals to bsums
__global__ void scan1_kernel(const int* __restrict__ hist, int* __restrict__ exc,
                             int* __restrict__ bsums, int n) {
    __shared__ int tmp[256];
    int t = threadIdx.x;
    int base = blockIdx.x * 1024 + t * 4;
    int v[4];
    int s = 0;
#pragma unroll
    for (int j = 0; j < 4; j++) {
        int idx = base + j;
        int h = (idx < n) ? hist[idx] : 0;
        v[j] = s;
        s += h;
    }
    tmp[t] = s;
    __syncthreads();
    for (int off = 1; off < 256; off <<= 1) {
        int x = 0;
        if (t >= off) x = tmp[t - off];
        __syncthreads();
        if (t >= off) tmp[t] += x;
        __syncthreads();
    }
    int texc = (t == 0) ? 0 : tmp[t - 1];
    if (t == 255) bsums[blockIdx.x] = tmp[255];
#pragma unroll
    for (int j = 0; j < 4; j++) {
        int idx = base + j;
        if (idx < n) exc[idx] = texc + v[j];
    }
}

// exclusive scan of block sums (nb <= 256), in place
__global__ void scan2_kernel(int* __restrict__ bsums, int nb) {
    __shared__ int tmp[256];
    int t = threadIdx.x;
    int val = (t < nb) ? bsums[t] : 0;
    tmp[t] = val;
    __syncthreads();
    for (int off = 1; off < 256; off <<= 1) {
        int x = 0;
        if (t >= off) x = tmp[t - off];
        __syncthreads();
        if (t >= off) tmp[t] += x;
        __syncthreads();
    }
    int excv = (t == 0) ? 0 : tmp[t - 1];
    if (t < nb) bsums[t] = excv;
}

__global__ void finalize_kernel(const int* __restrict__ hist, const int* __restrict__ boff,
                                int* __restrict__ rowptr, int* __restrict__ cursor,
                                float* __restrict__ dinv, int N, int E) {
    int i = blockIdx.x * blockDim.x + threadIdx.x;
    if (i < N) {
        int v = rowptr[i] + boff[i >> 10];
        rowptr[i] = v;
        cursor[i] = v;
        dinv[i] = rsqrtf((float)(hist[i] + 1));  // +1 self loop; deg >= 1 always
    }
    if (i == 0) rowptr[N] = E;
}

__global__ void place_kernel(const int* __restrict__ src, const int* __restrict__ dst,
                             int* __restrict__ cursor, int* __restrict__ ssrc, int E) {
    int i = blockIdx.x * blockDim.x + threadIdx.x;
    if (i < E) {
        int pos = atomicAdd(&cursor[dst[i]], 1);
        ssrc[pos] = src[i];
    }
}

// ---- GEMM + per-row scale:  out[r,:] = (X[r,:] @ W) * dinv[r] --------------
// X: [N,128] row-major, W: [128,DOUT] row-major.
// Block: 8 * (DOUT/4) threads. Each thread: 4 rows x 4 cols register tile.
// W staged in 32-row K-chunks; X tile staged transposed (padded stride).

template <int DOUT>
__launch_bounds__(256) __global__
void gemm_scale_kernel(const float* __restrict__ X, const float* __restrict__ W,
                       const float* __restrict__ dinv, float* __restrict__ out, int N) {
    constexpr int K = KDIM;
    constexpr int ROWS = 32;
    constexpr int XS = ROWS + 2;  // padded stride (floats) to break bank conflicts
    constexpr int KC = 32;        // K-chunk rows of W staged at a time
    __shared__ float Xl[K * XS];
    __shared__ float Wl[KC * DOUT];

    const int T = blockDim.x;
    const int t = threadIdx.x;
    const int rowbase = blockIdx.x * ROWS;

    // stage X tile transposed: Xl[k*XS + r] = X[rowbase+r][k]
    for (int i = t; i < ROWS * (K / 4); i += T) {
        int r = i >> 5;     // K/4 == 32 float4 per row
        int kg = i & 31;
        int rr = rowbase + r;
        float4 v;
        if (rr < N)
            v = *(const float4*)(X + (size_t)rr * K + kg * 4);
        else
            v = make_float4(0.f, 0.f, 0.f, 0.f);
        int k = kg * 4;
        Xl[(k + 0) * XS + r] = v.x;
        Xl[(k + 1) * XS + r] = v.y;
        Xl[(k + 2) * XS + r] = v.z;
        Xl[(k + 3) * XS + r] = v.w;
    }

    const int rg = t & 7;
    const int cg = t >> 3;
    const int r0 = rg * 4;
    const int c0 = cg * 4;
    float acc[4][4] = {{0.f}};

    for (int kc = 0; kc < K; kc += KC) {
        __syncthreads();  // protects Wl reuse (and first-time X staging)
        for (int i = t; i < KC * DOUT / 4; i += T) {
            ((float4*)Wl)[i] = *(const float4*)(W + kc * DOUT + i * 4);
        }
        __syncthreads();
#pragma unroll
        for (int k = 0; k < KC; k++) {
            const float4 w = *(const float4*)(&Wl[k * DOUT + c0]);
            const int xb = (kc + k) * XS + r0;
            float x0 = Xl[xb + 0];
            float x1 = Xl[xb + 1];
            float x2 = Xl[xb + 2];
            float x3 = Xl[xb + 3];
            acc[0][0] += x0 * w.x; acc[0][1] += x0 * w.y; acc[0][2] += x0 * w.z; acc[0][3] += x0 * w.w;
            acc[1][0] += x1 * w.x; acc[1][1] += x1 * w.y; acc[1][2] += x1 * w.z; acc[1][3] += x1 * w.w;
            acc[2][0] += x2 * w.x; acc[2][1] += x2 * w.y; acc[2][2] += x2 * w.z; acc[2][3] += x2 * w.w;
            acc[3][0] += x3 * w.x; acc[3][1] += x3 * w.y; acc[3][2] += x3 * w.z; acc[3][3] += x3 * w.w;
        }
    }

#pragma unroll
    for (int j = 0; j < 4; j++) {
        int row = rowbase + r0 + j;
        if (row < N) {
            float di = dinv[row];
            float4 o;
            o.x = acc[j][0] * di;
            o.y = acc[j][1] * di;
            o.z = acc[j][2] * di;
            o.w = acc[j][3] * di;
            *(float4*)(out + (size_t)row * DOUT + c0) = o;
        }
    }
}

// ---- Aggregation: out[i] = act(dinv[i]*(sum_{e} hs[src[e]] + hs[i]) + b) ---
// One group of DOUT/4 threads per node; float4 per lane.

template <int DOUT, bool RELU>
__launch_bounds__(256) __global__
void agg_kernel(const float* __restrict__ hs, const int* __restrict__ rowptr,
                const int* __restrict__ ssrc, const float* __restrict__ dinv,
                const float* __restrict__ bias, float* __restrict__ out, int N) {
    constexpr int TPN = DOUT / 4;
    const int npb = blockDim.x / TPN;
    const int node = blockIdx.x * npb + threadIdx.x / TPN;
    if (node >= N) return;
    const int lane = threadIdx.x % TPN;
    const int c0 = lane * 4;

    float4 acc = *(const float4*)(hs + (size_t)node * DOUT + c0);  // self loop
    const int e0 = rowptr[node];
    const int e1 = rowptr[node + 1];
    for (int e = e0; e < e1; e++) {
        int s = ssrc[e];
        const float4 v = *(const float4*)(hs + (size_t)s * DOUT + c0);
        acc.x += v.x; acc.y += v.y; acc.z += v.z; acc.w += v.w;
    }
    const float di = dinv[node];
    const float4 b = *(const float4*)(bias + c0);
    float4 o;
    o.x = di * acc.x + b.x;
    o.y = di * acc.y + b.y;
    o.z = di * acc.z + b.z;
    o.w = di * acc.w + b.w;
    if (RELU) {
        o.x = fmaxf(o.x, 0.f);
        o.y = fmaxf(o.y, 0.f);
        o.z = fmaxf(o.z, 0.f);
        o.w = fmaxf(o.w, 0.f);
    }
    *(float4*)(out + (size_t)node * DOUT + c0) = o;
}

// ---------------------------------------------------------------------------

extern "C" void kernel_launch(void* const* d_in, const int* in_sizes, int n_in,
                              void* d_out, int out_size, void* d_ws, size_t ws_size,
                              hipStream_t stream) {
    const float* x  = (const float*)d_in[0];
    const int*   ei = (const int*)d_in[1];   // [2,E] int (harness converts integer inputs)
    // d_in[2] = batch (unused)
    const float* W1 = (const float*)d_in[3];
    const float* b1 = (const float*)d_in[4];
    const float* W2 = (const float*)d_in[5];
    const float* b2 = (const float*)d_in[6];
    float* out = (float*)d_out;

    const int N = in_sizes[0] / KDIM;  // 100000
    const int E = in_sizes[1] / 2;     // 1600000
    const int* esrc = ei;
    const int* edst = ei + E;

    // workspace layout (512B aligned)
    char* ws = (char*)d_ws;
    size_t off = 0;
    auto alloc = [&](size_t bytes) {
        size_t p = off;
        off = (off + bytes + 511) & ~(size_t)511;
        return p;
    };
    int*   hist   = (int*)(ws + alloc((size_t)N * 4));
    int*   rowptr = (int*)(ws + alloc((size_t)(N + 1) * 4));
    int*   cursor = (int*)(ws + alloc((size_t)N * 4));
    float* dinv   = (float*)(ws + alloc((size_t)N * 4));
    int*   bsums  = (int*)(ws + alloc(256 * 4));
    int*   ssrc   = (int*)(ws + alloc((size_t)E * 4));
    float* hs     = (float*)(ws + alloc((size_t)N * KDIM * 4));  // reused: hs1 then hs2
    float* out1   = (float*)(ws + alloc((size_t)N * KDIM * 4));
    (void)ws_size;
    (void)n_in;
    (void)out_size;

    const int nb = (N + 1023) / 1024;

    hipMemsetAsync(hist, 0, (size_t)N * 4, stream);

    hist_kernel<<<(E + 255) / 256, 256, 0, stream>>>(edst, hist, E);
    scan1_kernel<<<nb, 256, 0, stream>>>(hist, rowptr, bsums, N);
    scan2_kernel<<<1, 256, 0, stream>>>(bsums, nb);
    finalize_kernel<<<(N + 255) / 256, 256, 0, stream>>>(hist, bsums, rowptr, cursor, dinv, N, E);
    place_kernel<<<(E + 255) / 256, 256, 0, stream>>>(esrc, edst, cursor, ssrc, E);

    // layer 1: hs1 = (x @ W1) * dinv ; out1 = relu(dinv*(gather + self) + b1)
    gemm_scale_kernel<128><<<(N + 31) / 32, 256, 0, stream>>>(x, W1, dinv, hs, N);
    agg_kernel<128, true><<<(N + 7) / 8, 256, 0, stream>>>(hs, rowptr, ssrc, dinv, b1, out1, N);

    // layer 2: hs2 = (out1 @ W2) * dinv ; out = dinv*(gather + self) + b2
    gemm_scale_kernel<64><<<(N + 31) / 32, 128, 0, stream>>>(out1, W2, dinv, hs, N);
    agg_kernel<64, false><<<(N + 15) / 16, 256, 0, stream>>>(hs, rowptr, ssrc, dinv, b2, out, N);
}

// Round 2
// 475.001 us; speedup vs baseline: 1.2202x; 1.2202x over previous
//
#include <hip/hip_runtime.h>

// ---------------------------------------------------------------------------
// GCN 2-layer forward on MI355X.
//   CSR build: 2-level bucket sort (bucket = dst>>9, 512 nodes/bucket).
//     bcount/bscan: bucket histogram + tiny scan (LDS-aggregated atomics).
//     bscatter: LDS radix-partition of edges into bucket regions (coalesced
//               writes of packed src|dstlow words, ~6.4 MB instead of the
//               102 MB random-scatter traffic of the old place_kernel).
//     bplace:   one block per bucket; node counts, scan, rowptr, dinv and
//               fine placement all in LDS; ssrc scatter confined to ~33 KB
//               (L2-resident) per bucket.
//   hs = (X @ W) * dinv[row]   (LDS-tiled fp32 GEMM, 4x4 register tile)
//   out[i] = act(dinv[i] * (sum_{j->i} hs[j] + hs[i]) + b)   (gather)
// ---------------------------------------------------------------------------

#define KDIM 128
#define BSHIFT 9
#define BSIZE 512              // nodes per bucket
#define ECHUNK 8192            // edges per bscatter/bcount block
#define PACK_SHIFT 20
#define PACK_MASK ((1u << PACK_SHIFT) - 1)

// ---- bucket histogram -----------------------------------------------------

__global__ void bcount_kernel(const int* __restrict__ dst, int* __restrict__ bhist,
                              int E, int NB) {
    __shared__ int lcnt[256];
    const int t = threadIdx.x;
    lcnt[t] = 0;
    __syncthreads();
    const int base = blockIdx.x * ECHUNK;
#pragma unroll
    for (int j = 0; j < ECHUNK / 256; j++) {
        int e = base + j * 256 + t;
        if (e < E) atomicAdd(&lcnt[dst[e] >> BSHIFT], 1);
    }
    __syncthreads();
    if (t < NB && lcnt[t]) atomicAdd(&bhist[t], lcnt[t]);
}

// exclusive scan of bucket hist (NB <= 256); writes bbase[NB]=E, bcursor copy
__global__ void bscan_kernel(const int* __restrict__ bhist, int* __restrict__ bbase,
                             int* __restrict__ bcursor, int NB, int E) {
    __shared__ int tmp[256];
    const int t = threadIdx.x;
    tmp[t] = (t < NB) ? bhist[t] : 0;
    __syncthreads();
    for (int off = 1; off < 256; off <<= 1) {
        int x = (t >= off) ? tmp[t - off] : 0;
        __syncthreads();
        if (t >= off) tmp[t] += x;
        __syncthreads();
    }
    int exc = (t == 0) ? 0 : tmp[t - 1];
    if (t < NB) {
        bbase[t] = exc;
        bcursor[t] = exc;
    }
    if (t == 0) bbase[NB] = E;
}

// ---- radix-partition edges into bucket regions ----------------------------

__launch_bounds__(256) __global__
void bscatter_kernel(const int* __restrict__ src, const int* __restrict__ dst,
                     int* __restrict__ bcursor, unsigned int* __restrict__ packed_out,
                     int E, int NB) {
    __shared__ int lcnt[256];               // per-bucket count, then local cursor
    __shared__ int lexc[256];               // per-bucket exclusive scan (local)
    __shared__ int lbase[256];              // per-bucket global base for this block
    __shared__ unsigned int lpacked[ECHUNK];
    __shared__ unsigned char lbslot[ECHUNK];

    const int t = threadIdx.x;
    lcnt[t] = 0;
    __syncthreads();

    const int base = blockIdx.x * ECHUNK;
    const int cnt = min(ECHUNK, E - base);

#pragma unroll
    for (int j = 0; j < ECHUNK / 256; j++) {
        int e = base + j * 256 + t;
        if (e < E) atomicAdd(&lcnt[dst[e] >> BSHIFT], 1);
    }
    __syncthreads();

    // exclusive scan of lcnt -> lexc
    lexc[t] = lcnt[t];
    __syncthreads();
    for (int off = 1; off < 256; off <<= 1) {
        int x = (t >= off) ? lexc[t - off] : 0;
        __syncthreads();
        if (t >= off) lexc[t] += x;
        __syncthreads();
    }
    int inc = lexc[t];
    __syncthreads();
    lexc[t] = inc - lcnt[t];

    // reserve this block's chunk in each bucket's global region
    if (t < NB && lcnt[t]) lbase[t] = atomicAdd(&bcursor[t], lcnt[t]);

    lcnt[t] = lexc[t];  // becomes the local placement cursor
    __syncthreads();

    // local reorder into LDS, grouped by bucket
#pragma unroll
    for (int j = 0; j < ECHUNK / 256; j++) {
        int e = base + j * 256 + t;
        if (e < E) {
            int d = dst[e];
            int b = d >> BSHIFT;
            int pos = atomicAdd(&lcnt[b], 1);
            lpacked[pos] = (unsigned int)src[e] | ((unsigned int)(d & (BSIZE - 1)) << PACK_SHIFT);
            lbslot[pos] = (unsigned char)b;
        }
    }
    __syncthreads();

    // write out: per-bucket runs are contiguous -> mostly coalesced
#pragma unroll
    for (int j = 0; j < ECHUNK / 256; j++) {
        int s = j * 256 + t;
        if (s < cnt) {
            int b = lbslot[s];
            packed_out[lbase[b] + (s - lexc[b])] = lpacked[s];
        }
    }
}

// ---- per-bucket fine placement + rowptr + dinv ----------------------------

__launch_bounds__(256) __global__
void bplace_kernel(const unsigned int* __restrict__ packed, const int* __restrict__ bbase,
                   int* __restrict__ rowptr, float* __restrict__ dinv,
                   int* __restrict__ ssrc, int N, int E) {
    __shared__ int ncnt[BSIZE];
    __shared__ int nexc[BSIZE];
    __shared__ int s1[256];

    const int t = threadIdx.x;
    const int b = blockIdx.x;
    ncnt[t] = 0;
    ncnt[t + 256] = 0;
    __syncthreads();

    const int e0 = bbase[b];
    const int e1 = bbase[b + 1];
    for (int e = e0 + t; e < e1; e += 256) {
        atomicAdd(&ncnt[packed[e] >> PACK_SHIFT], 1);
    }
    __syncthreads();

    // exclusive scan of 512 node counts (2 per thread)
    const int a0 = ncnt[2 * t];
    const int a1 = ncnt[2 * t + 1];
    s1[t] = a0 + a1;
    __syncthreads();
    for (int off = 1; off < 256; off <<= 1) {
        int x = (t >= off) ? s1[t - off] : 0;
        __syncthreads();
        if (t >= off) s1[t] += x;
        __syncthreads();
    }
    const int base2 = (t == 0) ? 0 : s1[t - 1];
    nexc[2 * t] = base2;
    nexc[2 * t + 1] = base2 + a0;

    // rowptr / dinv for this bucket's nodes (same-thread slots, no sync needed)
    const int nodebase = b * BSIZE;
    const int n0 = nodebase + 2 * t;
    const int n1 = n0 + 1;
    if (n0 < N) {
        rowptr[n0] = e0 + base2;
        dinv[n0] = rsqrtf((float)(a0 + 1));
    }
    if (n1 < N) {
        rowptr[n1] = e0 + base2 + a0;
        dinv[n1] = rsqrtf((float)(a1 + 1));
    }
    if (b == 0 && t == 0) rowptr[N] = E;
    __syncthreads();

    // fine placement; nexc doubles as cursor. ssrc region is ~33 KB -> L2.
    for (int e = e0 + t; e < e1; e += 256) {
        unsigned int p = packed[e];
        int d = p >> PACK_SHIFT;
        int pos = e0 + atomicAdd(&nexc[d], 1);
        ssrc[pos] = (int)(p & PACK_MASK);
    }
}

// ---- GEMM + per-row scale:  out[r,:] = (X[r,:] @ W) * dinv[r] --------------

template <int DOUT>
__launch_bounds__(256) __global__
void gemm_scale_kernel(const float* __restrict__ X, const float* __restrict__ W,
                       const float* __restrict__ dinv, float* __restrict__ out, int N) {
    constexpr int K = KDIM;
    constexpr int ROWS = 32;
    constexpr int XS = ROWS + 2;
    constexpr int KC = 32;
    __shared__ float Xl[K * XS];
    __shared__ float Wl[KC * DOUT];

    const int T = blockDim.x;
    const int t = threadIdx.x;
    const int rowbase = blockIdx.x * ROWS;

    for (int i = t; i < ROWS * (K / 4); i += T) {
        int r = i >> 5;
        int kg = i & 31;
        int rr = rowbase + r;
        float4 v;
        if (rr < N)
            v = *(const float4*)(X + (size_t)rr * K + kg * 4);
        else
            v = make_float4(0.f, 0.f, 0.f, 0.f);
        int k = kg * 4;
        Xl[(k + 0) * XS + r] = v.x;
        Xl[(k + 1) * XS + r] = v.y;
        Xl[(k + 2) * XS + r] = v.z;
        Xl[(k + 3) * XS + r] = v.w;
    }

    const int rg = t & 7;
    const int cg = t >> 3;
    const int r0 = rg * 4;
    const int c0 = cg * 4;
    float acc[4][4] = {{0.f}};

    for (int kc = 0; kc < K; kc += KC) {
        __syncthreads();
        for (int i = t; i < KC * DOUT / 4; i += T) {
            ((float4*)Wl)[i] = *(const float4*)(W + kc * DOUT + i * 4);
        }
        __syncthreads();
#pragma unroll
        for (int k = 0; k < KC; k++) {
            const float4 w = *(const float4*)(&Wl[k * DOUT + c0]);
            const int xb = (kc + k) * XS + r0;
            float x0 = Xl[xb + 0];
            float x1 = Xl[xb + 1];
            float x2 = Xl[xb + 2];
            float x3 = Xl[xb + 3];
            acc[0][0] += x0 * w.x; acc[0][1] += x0 * w.y; acc[0][2] += x0 * w.z; acc[0][3] += x0 * w.w;
            acc[1][0] += x1 * w.x; acc[1][1] += x1 * w.y; acc[1][2] += x1 * w.z; acc[1][3] += x1 * w.w;
            acc[2][0] += x2 * w.x; acc[2][1] += x2 * w.y; acc[2][2] += x2 * w.z; acc[2][3] += x2 * w.w;
            acc[3][0] += x3 * w.x; acc[3][1] += x3 * w.y; acc[3][2] += x3 * w.z; acc[3][3] += x3 * w.w;
        }
    }

#pragma unroll
    for (int j = 0; j < 4; j++) {
        int row = rowbase + r0 + j;
        if (row < N) {
            float di = dinv[row];
            float4 o;
            o.x = acc[j][0] * di;
            o.y = acc[j][1] * di;
            o.z = acc[j][2] * di;
            o.w = acc[j][3] * di;
            *(float4*)(out + (size_t)row * DOUT + c0) = o;
        }
    }
}

// ---- Aggregation: out[i] = act(dinv[i]*(sum_e hs[src[e]] + hs[i]) + b) ----

template <int DOUT, bool RELU>
__launch_bounds__(256) __global__
void agg_kernel(const float* __restrict__ hs, const int* __restrict__ rowptr,
                const int* __restrict__ ssrc, const float* __restrict__ dinv,
                const float* __restrict__ bias, float* __restrict__ out, int N) {
    constexpr int TPN = DOUT / 4;
    const int npb = blockDim.x / TPN;
    const int node = blockIdx.x * npb + threadIdx.x / TPN;
    if (node >= N) return;
    const int lane = threadIdx.x % TPN;
    const int c0 = lane * 4;

    float4 acc = *(const float4*)(hs + (size_t)node * DOUT + c0);  // self loop
    const int e0 = rowptr[node];
    const int e1 = rowptr[node + 1];
    for (int e = e0; e < e1; e++) {
        int s = ssrc[e];
        const float4 v = *(const float4*)(hs + (size_t)s * DOUT + c0);
        acc.x += v.x; acc.y += v.y; acc.z += v.z; acc.w += v.w;
    }
    const float di = dinv[node];
    const float4 b = *(const float4*)(bias + c0);
    float4 o;
    o.x = di * acc.x + b.x;
    o.y = di * acc.y + b.y;
    o.z = di * acc.z + b.z;
    o.w = di * acc.w + b.w;
    if (RELU) {
        o.x = fmaxf(o.x, 0.f);
        o.y = fmaxf(o.y, 0.f);
        o.z = fmaxf(o.z, 0.f);
        o.w = fmaxf(o.w, 0.f);
    }
    *(float4*)(out + (size_t)node * DOUT + c0) = o;
}

// ---------------------------------------------------------------------------

extern "C" void kernel_launch(void* const* d_in, const int* in_sizes, int n_in,
                              void* d_out, int out_size, void* d_ws, size_t ws_size,
                              hipStream_t stream) {
    const float* x  = (const float*)d_in[0];
    const int*   ei = (const int*)d_in[1];   // [2,E], harness converts int64 -> int32
    const float* W1 = (const float*)d_in[3];
    const float* b1 = (const float*)d_in[4];
    const float* W2 = (const float*)d_in[5];
    const float* b2 = (const float*)d_in[6];
    float* out = (float*)d_out;

    const int N = in_sizes[0] / KDIM;  // 100000
    const int E = in_sizes[1] / 2;     // 1600000
    const int* esrc = ei;
    const int* edst = ei + E;
    const int NB = (N + BSIZE - 1) >> BSHIFT;  // 196

    // workspace layout (512B aligned)
    char* ws = (char*)d_ws;
    size_t off = 0;
    auto alloc = [&](size_t bytes) {
        size_t p = off;
        off = (off + bytes + 511) & ~(size_t)511;
        return p;
    };
    int*   bhist   = (int*)(ws + alloc((size_t)NB * 4));
    int*   bbase   = (int*)(ws + alloc((size_t)(NB + 1) * 4));
    int*   bcursor = (int*)(ws + alloc((size_t)NB * 4));
    int*   rowptr  = (int*)(ws + alloc((size_t)(N + 1) * 4));
    float* dinv    = (float*)(ws + alloc((size_t)N * 4));
    int*   ssrc    = (int*)(ws + alloc((size_t)E * 4));
    float* hs      = (float*)(ws + alloc((size_t)N * KDIM * 4));  // hs1, then hs2
    float* out1    = (float*)(ws + alloc((size_t)N * KDIM * 4));
    // packed edge words alias hs: consumed by bplace before gemm writes hs
    unsigned int* packed = (unsigned int*)hs;
    (void)ws_size; (void)n_in; (void)out_size;

    const int eb = (E + ECHUNK - 1) / ECHUNK;  // 196

    hipMemsetAsync(bhist, 0, (size_t)NB * 4, stream);

    bcount_kernel<<<eb, 256, 0, stream>>>(edst, bhist, E, NB);
    bscan_kernel<<<1, 256, 0, stream>>>(bhist, bbase, bcursor, NB, E);
    bscatter_kernel<<<eb, 256, 0, stream>>>(esrc, edst, bcursor, packed, E, NB);
    bplace_kernel<<<NB, 256, 0, stream>>>(packed, bbase, rowptr, dinv, ssrc, N, E);

    // layer 1: hs1 = (x @ W1) * dinv ; out1 = relu(dinv*(gather + self) + b1)
    gemm_scale_kernel<128><<<(N + 31) / 32, 256, 0, stream>>>(x, W1, dinv, hs, N);
    agg_kernel<128, true><<<(N + 7) / 8, 256, 0, stream>>>(hs, rowptr, ssrc, dinv, b1, out1, N);

    // layer 2: hs2 = (out1 @ W2) * dinv ; out = dinv*(gather + self) + b2
    gemm_scale_kernel<64><<<(N + 31) / 32, 128, 0, stream>>>(out1, W2, dinv, hs, N);
    agg_kernel<64, false><<<(N + 15) / 16, 256, 0, stream>>>(hs, rowptr, ssrc, dinv, b2, out, N);
}

// Round 3
// 452.920 us; speedup vs baseline: 1.2797x; 1.0488x over previous
//
#include <hip/hip_runtime.h>

// ---------------------------------------------------------------------------
// GCN 2-layer forward on MI355X.
//   CSR build: 2-level bucket sort (bucket = dst>>9, 512 nodes/bucket).
//   hs = (X @ W) * dinv[row]   (LDS-tiled fp32 GEMM, 8x8 register tile,
//                               all-b128 LDS reads, KC=32 K-chunks)
//   out[i] = act(dinv[i] * (sum_{j->i} hs[j] + hs[i]) + b)
//            (gather, unroll-4 with independent accumulators for MLP)
// ---------------------------------------------------------------------------

#define KDIM 128
#define BSHIFT 9
#define BSIZE 512
#define ECHUNK 8192
#define PACK_SHIFT 20
#define PACK_MASK ((1u << PACK_SHIFT) - 1)

// ---- bucket histogram -----------------------------------------------------

__global__ void bcount_kernel(const int* __restrict__ dst, int* __restrict__ bhist,
                              int E, int NB) {
    __shared__ int lcnt[256];
    const int t = threadIdx.x;
    lcnt[t] = 0;
    __syncthreads();
    const int base = blockIdx.x * ECHUNK;
#pragma unroll
    for (int j = 0; j < ECHUNK / 256; j++) {
        int e = base + j * 256 + t;
        if (e < E) atomicAdd(&lcnt[dst[e] >> BSHIFT], 1);
    }
    __syncthreads();
    if (t < NB && lcnt[t]) atomicAdd(&bhist[t], lcnt[t]);
}

__global__ void bscan_kernel(const int* __restrict__ bhist, int* __restrict__ bbase,
                             int* __restrict__ bcursor, int NB, int E) {
    __shared__ int tmp[256];
    const int t = threadIdx.x;
    tmp[t] = (t < NB) ? bhist[t] : 0;
    __syncthreads();
    for (int off = 1; off < 256; off <<= 1) {
        int x = (t >= off) ? tmp[t - off] : 0;
        __syncthreads();
        if (t >= off) tmp[t] += x;
        __syncthreads();
    }
    int exc = (t == 0) ? 0 : tmp[t - 1];
    if (t < NB) {
        bbase[t] = exc;
        bcursor[t] = exc;
    }
    if (t == 0) bbase[NB] = E;
}

// ---- radix-partition edges into bucket regions ----------------------------

__launch_bounds__(256) __global__
void bscatter_kernel(const int* __restrict__ src, const int* __restrict__ dst,
                     int* __restrict__ bcursor, unsigned int* __restrict__ packed_out,
                     int E, int NB) {
    __shared__ int lcnt[256];
    __shared__ int lexc[256];
    __shared__ int lbase[256];
    __shared__ unsigned int lpacked[ECHUNK];
    __shared__ unsigned char lbslot[ECHUNK];

    const int t = threadIdx.x;
    lcnt[t] = 0;
    __syncthreads();

    const int base = blockIdx.x * ECHUNK;
    const int cnt = min(ECHUNK, E - base);

#pragma unroll
    for (int j = 0; j < ECHUNK / 256; j++) {
        int e = base + j * 256 + t;
        if (e < E) atomicAdd(&lcnt[dst[e] >> BSHIFT], 1);
    }
    __syncthreads();

    lexc[t] = lcnt[t];
    __syncthreads();
    for (int off = 1; off < 256; off <<= 1) {
        int x = (t >= off) ? lexc[t - off] : 0;
        __syncthreads();
        if (t >= off) lexc[t] += x;
        __syncthreads();
    }
    int inc = lexc[t];
    __syncthreads();
    lexc[t] = inc - lcnt[t];

    if (t < NB && lcnt[t]) lbase[t] = atomicAdd(&bcursor[t], lcnt[t]);

    lcnt[t] = lexc[t];
    __syncthreads();

#pragma unroll
    for (int j = 0; j < ECHUNK / 256; j++) {
        int e = base + j * 256 + t;
        if (e < E) {
            int d = dst[e];
            int b = d >> BSHIFT;
            int pos = atomicAdd(&lcnt[b], 1);
            lpacked[pos] = (unsigned int)src[e] | ((unsigned int)(d & (BSIZE - 1)) << PACK_SHIFT);
            lbslot[pos] = (unsigned char)b;
        }
    }
    __syncthreads();

#pragma unroll
    for (int j = 0; j < ECHUNK / 256; j++) {
        int s = j * 256 + t;
        if (s < cnt) {
            int b = lbslot[s];
            packed_out[lbase[b] + (s - lexc[b])] = lpacked[s];
        }
    }
}

// ---- per-bucket fine placement + rowptr + dinv ----------------------------

__launch_bounds__(256) __global__
void bplace_kernel(const unsigned int* __restrict__ packed, const int* __restrict__ bbase,
                   int* __restrict__ rowptr, float* __restrict__ dinv,
                   int* __restrict__ ssrc, int N, int E) {
    __shared__ int ncnt[BSIZE];
    __shared__ int nexc[BSIZE];
    __shared__ int s1[256];

    const int t = threadIdx.x;
    const int b = blockIdx.x;
    ncnt[t] = 0;
    ncnt[t + 256] = 0;
    __syncthreads();

    const int e0 = bbase[b];
    const int e1 = bbase[b + 1];
    for (int e = e0 + t; e < e1; e += 256) {
        atomicAdd(&ncnt[packed[e] >> PACK_SHIFT], 1);
    }
    __syncthreads();

    const int a0 = ncnt[2 * t];
    const int a1 = ncnt[2 * t + 1];
    s1[t] = a0 + a1;
    __syncthreads();
    for (int off = 1; off < 256; off <<= 1) {
        int x = (t >= off) ? s1[t - off] : 0;
        __syncthreads();
        if (t >= off) s1[t] += x;
        __syncthreads();
    }
    const int base2 = (t == 0) ? 0 : s1[t - 1];
    nexc[2 * t] = base2;
    nexc[2 * t + 1] = base2 + a0;

    const int nodebase = b * BSIZE;
    const int n0 = nodebase + 2 * t;
    const int n1 = n0 + 1;
    if (n0 < N) {
        rowptr[n0] = e0 + base2;
        dinv[n0] = rsqrtf((float)(a0 + 1));
    }
    if (n1 < N) {
        rowptr[n1] = e0 + base2 + a0;
        dinv[n1] = rsqrtf((float)(a1 + 1));
    }
    if (b == 0 && t == 0) rowptr[N] = E;
    __syncthreads();

    for (int e = e0 + t; e < e1; e += 256) {
        unsigned int p = packed[e];
        int d = p >> PACK_SHIFT;
        int pos = e0 + atomicAdd(&nexc[d], 1);
        ssrc[pos] = (int)(p & PACK_MASK);
    }
}

// ---- GEMM + per-row scale:  out[r,:] = (X[r,:] @ W) * dinv[r] --------------
// 128-row block, 256 threads, thread tile 8 rows x (DOUT/16) cols.
// K chunked by 32; X chunk staged transposed [k][r] (stride 132), W chunk
// staged [k][c]. All inner-loop LDS reads are ds_read_b128.

template <int DOUT>
__launch_bounds__(256) __global__
void gemm_scale_kernel(const float* __restrict__ X, const float* __restrict__ W,
                       const float* __restrict__ dinv, float* __restrict__ out, int N) {
    constexpr int K = KDIM;        // 128
    constexpr int ROWS = 128;
    constexpr int KC = 32;
    constexpr int XS = ROWS + 4;   // 132: keeps float4 alignment for r0 = 8*rg
    constexpr int CPT = DOUT / 16; // cols per thread: 8 (DOUT=128) or 4 (DOUT=64)
    __shared__ float Xl[KC * XS];
    __shared__ float Wl[KC * DOUT];

    const int t = threadIdx.x;
    const int rowbase = blockIdx.x * ROWS;
    const int rg = t & 15;
    const int cg = t >> 4;
    const int r0 = rg * 8;
    const int c0 = cg * CPT;

    float acc[8][CPT];
#pragma unroll
    for (int j = 0; j < 8; j++)
#pragma unroll
        for (int c = 0; c < CPT; c++) acc[j][c] = 0.f;

    for (int kc = 0; kc < K; kc += KC) {
        __syncthreads();
        // stage W chunk
#pragma unroll
        for (int i = t; i < KC * DOUT / 4; i += 256) {
            ((float4*)Wl)[i] = ((const float4*)(W + (size_t)kc * DOUT))[i];
        }
        // stage X chunk transposed: Xl[k*XS + r] = X[rowbase+r][kc+k]
#pragma unroll
        for (int i = t; i < ROWS * (KC / 4); i += 256) {  // 1024 -> 4 iters
            int r = i >> 3;
            int kg = i & 7;
            int rr = rowbase + r;
            float4 v;
            if (rr < N)
                v = *(const float4*)(X + (size_t)rr * K + kc + kg * 4);
            else
                v = make_float4(0.f, 0.f, 0.f, 0.f);
            int k = kg * 4;
            Xl[(k + 0) * XS + r] = v.x;
            Xl[(k + 1) * XS + r] = v.y;
            Xl[(k + 2) * XS + r] = v.z;
            Xl[(k + 3) * XS + r] = v.w;
        }
        __syncthreads();

#pragma unroll
        for (int k = 0; k < KC; k++) {
            const float4 xa = *(const float4*)(&Xl[k * XS + r0]);
            const float4 xb = *(const float4*)(&Xl[k * XS + r0 + 4]);
            float xr[8] = {xa.x, xa.y, xa.z, xa.w, xb.x, xb.y, xb.z, xb.w};
            float wr[CPT];
            const float4 wa = *(const float4*)(&Wl[k * DOUT + c0]);
            wr[0] = wa.x; wr[1] = wa.y; wr[2] = wa.z; wr[3] = wa.w;
            if (CPT == 8) {
                const float4 wb = *(const float4*)(&Wl[k * DOUT + c0 + 4]);
                wr[4] = wb.x; wr[5] = wb.y; wr[6] = wb.z; wr[7] = wb.w;
            }
#pragma unroll
            for (int j = 0; j < 8; j++)
#pragma unroll
                for (int c = 0; c < CPT; c++)
                    acc[j][c] += xr[j] * wr[c];
        }
    }

#pragma unroll
    for (int j = 0; j < 8; j++) {
        int row = rowbase + r0 + j;
        if (row < N) {
            float di = dinv[row];
            float* op = out + (size_t)row * DOUT + c0;
#pragma unroll
            for (int c4 = 0; c4 < CPT; c4 += 4) {
                float4 o;
                o.x = acc[j][c4 + 0] * di;
                o.y = acc[j][c4 + 1] * di;
                o.z = acc[j][c4 + 2] * di;
                o.w = acc[j][c4 + 3] * di;
                *(float4*)(op + c4) = o;
            }
        }
    }
}

// ---- Aggregation: out[i] = act(dinv[i]*(sum_e hs[src[e]] + hs[i]) + b) ----
// Unroll-4 with independent accumulators: 4 index loads + 4 row gathers in
// flight per thread instead of 1 -> memory-level parallelism for the
// latency-bound random gather.

template <int DOUT, bool RELU>
__launch_bounds__(256) __global__
void agg_kernel(const float* __restrict__ hs, const int* __restrict__ rowptr,
                const int* __restrict__ ssrc, const float* __restrict__ dinv,
                const float* __restrict__ bias, float* __restrict__ out, int N) {
    constexpr int TPN = DOUT / 4;
    const int npb = blockDim.x / TPN;
    const int node = blockIdx.x * npb + threadIdx.x / TPN;
    if (node >= N) return;
    const int lane = threadIdx.x % TPN;
    const int c0 = lane * 4;

    float4 a0 = *(const float4*)(hs + (size_t)node * DOUT + c0);  // self loop
    float4 a1 = make_float4(0.f, 0.f, 0.f, 0.f);
    float4 a2 = make_float4(0.f, 0.f, 0.f, 0.f);
    float4 a3 = make_float4(0.f, 0.f, 0.f, 0.f);

    const int e0 = rowptr[node];
    const int e1 = rowptr[node + 1];
    int e = e0;
    for (; e + 4 <= e1; e += 4) {
        int s0 = ssrc[e + 0];
        int s1 = ssrc[e + 1];
        int s2 = ssrc[e + 2];
        int s3 = ssrc[e + 3];
        const float4 v0 = *(const float4*)(hs + (size_t)s0 * DOUT + c0);
        const float4 v1 = *(const float4*)(hs + (size_t)s1 * DOUT + c0);
        const float4 v2 = *(const float4*)(hs + (size_t)s2 * DOUT + c0);
        const float4 v3 = *(const float4*)(hs + (size_t)s3 * DOUT + c0);
        a0.x += v0.x; a0.y += v0.y; a0.z += v0.z; a0.w += v0.w;
        a1.x += v1.x; a1.y += v1.y; a1.z += v1.z; a1.w += v1.w;
        a2.x += v2.x; a2.y += v2.y; a2.z += v2.z; a2.w += v2.w;
        a3.x += v3.x; a3.y += v3.y; a3.z += v3.z; a3.w += v3.w;
    }
    for (; e < e1; e++) {
        int s = ssrc[e];
        const float4 v = *(const float4*)(hs + (size_t)s * DOUT + c0);
        a0.x += v.x; a0.y += v.y; a0.z += v.z; a0.w += v.w;
    }
    float4 acc;
    acc.x = (a0.x + a1.x) + (a2.x + a3.x);
    acc.y = (a0.y + a1.y) + (a2.y + a3.y);
    acc.z = (a0.z + a1.z) + (a2.z + a3.z);
    acc.w = (a0.w + a1.w) + (a2.w + a3.w);

    const float di = dinv[node];
    const float4 b = *(const float4*)(bias + c0);
    float4 o;
    o.x = di * acc.x + b.x;
    o.y = di * acc.y + b.y;
    o.z = di * acc.z + b.z;
    o.w = di * acc.w + b.w;
    if (RELU) {
        o.x = fmaxf(o.x, 0.f);
        o.y = fmaxf(o.y, 0.f);
        o.z = fmaxf(o.z, 0.f);
        o.w = fmaxf(o.w, 0.f);
    }
    *(float4*)(out + (size_t)node * DOUT + c0) = o;
}

// ---------------------------------------------------------------------------

extern "C" void kernel_launch(void* const* d_in, const int* in_sizes, int n_in,
                              void* d_out, int out_size, void* d_ws, size_t ws_size,
                              hipStream_t stream) {
    const float* x  = (const float*)d_in[0];
    const int*   ei = (const int*)d_in[1];
    const float* W1 = (const float*)d_in[3];
    const float* b1 = (const float*)d_in[4];
    const float* W2 = (const float*)d_in[5];
    const float* b2 = (const float*)d_in[6];
    float* out = (float*)d_out;

    const int N = in_sizes[0] / KDIM;  // 100000
    const int E = in_sizes[1] / 2;     // 1600000
    const int* esrc = ei;
    const int* edst = ei + E;
    const int NB = (N + BSIZE - 1) >> BSHIFT;  // 196

    char* ws = (char*)d_ws;
    size_t off = 0;
    auto alloc = [&](size_t bytes) {
        size_t p = off;
        off = (off + bytes + 511) & ~(size_t)511;
        return p;
    };
    int*   bhist   = (int*)(ws + alloc((size_t)NB * 4));
    int*   bbase   = (int*)(ws + alloc((size_t)(NB + 1) * 4));
    int*   bcursor = (int*)(ws + alloc((size_t)NB * 4));
    int*   rowptr  = (int*)(ws + alloc((size_t)(N + 1) * 4));
    float* dinv    = (float*)(ws + alloc((size_t)N * 4));
    int*   ssrc    = (int*)(ws + alloc((size_t)E * 4));
    float* hs      = (float*)(ws + alloc((size_t)N * KDIM * 4));
    float* out1    = (float*)(ws + alloc((size_t)N * KDIM * 4));
    unsigned int* packed = (unsigned int*)hs;  // consumed before gemm writes hs
    (void)ws_size; (void)n_in; (void)out_size;

    const int eb = (E + ECHUNK - 1) / ECHUNK;

    hipMemsetAsync(bhist, 0, (size_t)NB * 4, stream);

    bcount_kernel<<<eb, 256, 0, stream>>>(edst, bhist, E, NB);
    bscan_kernel<<<1, 256, 0, stream>>>(bhist, bbase, bcursor, NB, E);
    bscatter_kernel<<<eb, 256, 0, stream>>>(esrc, edst, bcursor, packed, E, NB);
    bplace_kernel<<<NB, 256, 0, stream>>>(packed, bbase, rowptr, dinv, ssrc, N, E);

    // layer 1
    gemm_scale_kernel<128><<<(N + 127) / 128, 256, 0, stream>>>(x, W1, dinv, hs, N);
    agg_kernel<128, true><<<(N + 7) / 8, 256, 0, stream>>>(hs, rowptr, ssrc, dinv, b1, out1, N);

    // layer 2
    gemm_scale_kernel<64><<<(N + 127) / 128, 256, 0, stream>>>(out1, W2, dinv, hs, N);
    agg_kernel<64, false><<<(N + 15) / 16, 256, 0, stream>>>(hs, rowptr, ssrc, dinv, b2, out, N);
}

// Round 4
// 359.729 us; speedup vs baseline: 1.6112x; 1.2591x over previous
//
#include <hip/hip_runtime.h>
#include <hip/hip_fp16.h>

// ---------------------------------------------------------------------------
// GCN 2-layer forward on MI355X.
//   CSR build: 2-level bucket sort (bucket = dst>>9, 512 nodes/bucket).
//   hs = fp16[(X @ W) * dinv[row]]  (fp32 LDS-tiled GEMM, 8x8 register tile,
//                                    fp16-packed epilogue -> halves the
//                                    L2-miss traffic of the random gather)
//   out[i] = act(dinv[i] * (sum_{j->i} hs[j] + hs[i]) + b)
//            (gather in fp16, fp32 accumulate, unroll-4)
// ---------------------------------------------------------------------------

#define KDIM 128
#define BSHIFT 9
#define BSIZE 512
#define ECHUNK 8192
#define PACK_SHIFT 20
#define PACK_MASK ((1u << PACK_SHIFT) - 1)

// ---- bucket histogram -----------------------------------------------------

__global__ void bcount_kernel(const int* __restrict__ dst, int* __restrict__ bhist,
                              int E, int NB) {
    __shared__ int lcnt[256];
    const int t = threadIdx.x;
    lcnt[t] = 0;
    __syncthreads();
    const int base = blockIdx.x * ECHUNK;
#pragma unroll
    for (int j = 0; j < ECHUNK / 256; j++) {
        int e = base + j * 256 + t;
        if (e < E) atomicAdd(&lcnt[dst[e] >> BSHIFT], 1);
    }
    __syncthreads();
    if (t < NB && lcnt[t]) atomicAdd(&bhist[t], lcnt[t]);
}

__global__ void bscan_kernel(const int* __restrict__ bhist, int* __restrict__ bbase,
                             int* __restrict__ bcursor, int NB, int E) {
    __shared__ int tmp[256];
    const int t = threadIdx.x;
    tmp[t] = (t < NB) ? bhist[t] : 0;
    __syncthreads();
    for (int off = 1; off < 256; off <<= 1) {
        int x = (t >= off) ? tmp[t - off] : 0;
        __syncthreads();
        if (t >= off) tmp[t] += x;
        __syncthreads();
    }
    int exc = (t == 0) ? 0 : tmp[t - 1];
    if (t < NB) {
        bbase[t] = exc;
        bcursor[t] = exc;
    }
    if (t == 0) bbase[NB] = E;
}

// ---- radix-partition edges into bucket regions ----------------------------

__launch_bounds__(256) __global__
void bscatter_kernel(const int* __restrict__ src, const int* __restrict__ dst,
                     int* __restrict__ bcursor, unsigned int* __restrict__ packed_out,
                     int E, int NB) {
    __shared__ int lcnt[256];
    __shared__ int lexc[256];
    __shared__ int lbase[256];
    __shared__ unsigned int lpacked[ECHUNK];
    __shared__ unsigned char lbslot[ECHUNK];

    const int t = threadIdx.x;
    lcnt[t] = 0;
    __syncthreads();

    const int base = blockIdx.x * ECHUNK;
    const int cnt = min(ECHUNK, E - base);

#pragma unroll
    for (int j = 0; j < ECHUNK / 256; j++) {
        int e = base + j * 256 + t;
        if (e < E) atomicAdd(&lcnt[dst[e] >> BSHIFT], 1);
    }
    __syncthreads();

    lexc[t] = lcnt[t];
    __syncthreads();
    for (int off = 1; off < 256; off <<= 1) {
        int x = (t >= off) ? lexc[t - off] : 0;
        __syncthreads();
        if (t >= off) lexc[t] += x;
        __syncthreads();
    }
    int inc = lexc[t];
    __syncthreads();
    lexc[t] = inc - lcnt[t];

    if (t < NB && lcnt[t]) lbase[t] = atomicAdd(&bcursor[t], lcnt[t]);

    lcnt[t] = lexc[t];
    __syncthreads();

#pragma unroll
    for (int j = 0; j < ECHUNK / 256; j++) {
        int e = base + j * 256 + t;
        if (e < E) {
            int d = dst[e];
            int b = d >> BSHIFT;
            int pos = atomicAdd(&lcnt[b], 1);
            lpacked[pos] = (unsigned int)src[e] | ((unsigned int)(d & (BSIZE - 1)) << PACK_SHIFT);
            lbslot[pos] = (unsigned char)b;
        }
    }
    __syncthreads();

#pragma unroll
    for (int j = 0; j < ECHUNK / 256; j++) {
        int s = j * 256 + t;
        if (s < cnt) {
            int b = lbslot[s];
            packed_out[lbase[b] + (s - lexc[b])] = lpacked[s];
        }
    }
}

// ---- per-bucket fine placement + rowptr + dinv ----------------------------

__launch_bounds__(256) __global__
void bplace_kernel(const unsigned int* __restrict__ packed, const int* __restrict__ bbase,
                   int* __restrict__ rowptr, float* __restrict__ dinv,
                   int* __restrict__ ssrc, int N, int E) {
    __shared__ int ncnt[BSIZE];
    __shared__ int nexc[BSIZE];
    __shared__ int s1[256];

    const int t = threadIdx.x;
    const int b = blockIdx.x;
    ncnt[t] = 0;
    ncnt[t + 256] = 0;
    __syncthreads();

    const int e0 = bbase[b];
    const int e1 = bbase[b + 1];
    for (int e = e0 + t; e < e1; e += 256) {
        atomicAdd(&ncnt[packed[e] >> PACK_SHIFT], 1);
    }
    __syncthreads();

    const int a0 = ncnt[2 * t];
    const int a1 = ncnt[2 * t + 1];
    s1[t] = a0 + a1;
    __syncthreads();
    for (int off = 1; off < 256; off <<= 1) {
        int x = (t >= off) ? s1[t - off] : 0;
        __syncthreads();
        if (t >= off) s1[t] += x;
        __syncthreads();
    }
    const int base2 = (t == 0) ? 0 : s1[t - 1];
    nexc[2 * t] = base2;
    nexc[2 * t + 1] = base2 + a0;

    const int nodebase = b * BSIZE;
    const int n0 = nodebase + 2 * t;
    const int n1 = n0 + 1;
    if (n0 < N) {
        rowptr[n0] = e0 + base2;
        dinv[n0] = rsqrtf((float)(a0 + 1));
    }
    if (n1 < N) {
        rowptr[n1] = e0 + base2 + a0;
        dinv[n1] = rsqrtf((float)(a1 + 1));
    }
    if (b == 0 && t == 0) rowptr[N] = E;
    __syncthreads();

    for (int e = e0 + t; e < e1; e += 256) {
        unsigned int p = packed[e];
        int d = p >> PACK_SHIFT;
        int pos = e0 + atomicAdd(&nexc[d], 1);
        ssrc[pos] = (int)(p & PACK_MASK);
    }
}

// ---- GEMM + per-row scale, fp16 output ------------------------------------
// outh[r,:] = fp16( (X[r,:] @ W) * dinv[r] )
// 128-row block, 256 threads, thread tile 8 rows x (DOUT/16) cols, fp32 math.

template <int DOUT>
__launch_bounds__(256) __global__
void gemm_scale_kernel(const float* __restrict__ X, const float* __restrict__ W,
                       const float* __restrict__ dinv, __half* __restrict__ outh, int N) {
    constexpr int K = KDIM;        // 128
    constexpr int ROWS = 128;
    constexpr int KC = 32;
    constexpr int XS = ROWS + 4;   // 132: keeps float4 alignment for r0 = 8*rg
    constexpr int CPT = DOUT / 16; // cols per thread: 8 (DOUT=128) or 4 (DOUT=64)
    __shared__ float Xl[KC * XS];
    __shared__ float Wl[KC * DOUT];

    const int t = threadIdx.x;
    const int rowbase = blockIdx.x * ROWS;
    const int rg = t & 15;
    const int cg = t >> 4;
    const int r0 = rg * 8;
    const int c0 = cg * CPT;

    float acc[8][CPT];
#pragma unroll
    for (int j = 0; j < 8; j++)
#pragma unroll
        for (int c = 0; c < CPT; c++) acc[j][c] = 0.f;

    for (int kc = 0; kc < K; kc += KC) {
        __syncthreads();
#pragma unroll
        for (int i = t; i < KC * DOUT / 4; i += 256) {
            ((float4*)Wl)[i] = ((const float4*)(W + (size_t)kc * DOUT))[i];
        }
#pragma unroll
        for (int i = t; i < ROWS * (KC / 4); i += 256) {
            int r = i >> 3;
            int kg = i & 7;
            int rr = rowbase + r;
            float4 v;
            if (rr < N)
                v = *(const float4*)(X + (size_t)rr * K + kc + kg * 4);
            else
                v = make_float4(0.f, 0.f, 0.f, 0.f);
            int k = kg * 4;
            Xl[(k + 0) * XS + r] = v.x;
            Xl[(k + 1) * XS + r] = v.y;
            Xl[(k + 2) * XS + r] = v.z;
            Xl[(k + 3) * XS + r] = v.w;
        }
        __syncthreads();

#pragma unroll
        for (int k = 0; k < KC; k++) {
            const float4 xa = *(const float4*)(&Xl[k * XS + r0]);
            const float4 xb = *(const float4*)(&Xl[k * XS + r0 + 4]);
            float xr[8] = {xa.x, xa.y, xa.z, xa.w, xb.x, xb.y, xb.z, xb.w};
            float wr[CPT];
            const float4 wa = *(const float4*)(&Wl[k * DOUT + c0]);
            wr[0] = wa.x; wr[1] = wa.y; wr[2] = wa.z; wr[3] = wa.w;
            if (CPT == 8) {
                const float4 wb = *(const float4*)(&Wl[k * DOUT + c0 + 4]);
                wr[4] = wb.x; wr[5] = wb.y; wr[6] = wb.z; wr[7] = wb.w;
            }
#pragma unroll
            for (int j = 0; j < 8; j++)
#pragma unroll
                for (int c = 0; c < CPT; c++)
                    acc[j][c] += xr[j] * wr[c];
        }
    }

#pragma unroll
    for (int j = 0; j < 8; j++) {
        int row = rowbase + r0 + j;
        if (row < N) {
            float di = dinv[row];
            __half2 h[CPT / 2];
#pragma unroll
            for (int c = 0; c < CPT; c += 2)
                h[c / 2] = __floats2half2_rn(acc[j][c] * di, acc[j][c + 1] * di);
            __half* op = outh + (size_t)row * DOUT + c0;
            if (CPT == 8)
                *(uint4*)op = *(uint4*)h;
            else
                *(uint2*)op = *(uint2*)h;
        }
    }
}

// ---- Aggregation: out[i] = act(dinv[i]*(sum_e hs[src[e]] + hs[i]) + b) ----
// hs is fp16; TPN = DOUT/8 lanes per node, 16 B (8 halves) per lane.
// fp32 accumulation; unroll-4 edge loop for load MLP.

template <int DOUT, bool RELU>
__launch_bounds__(256) __global__
void agg_kernel(const __half* __restrict__ hs, const int* __restrict__ rowptr,
                const int* __restrict__ ssrc, const float* __restrict__ dinv,
                const float* __restrict__ bias, float* __restrict__ out, int N) {
    constexpr int TPN = DOUT / 8;
    const int npb = blockDim.x / TPN;
    const int node = blockIdx.x * npb + threadIdx.x / TPN;
    if (node >= N) return;
    const int lane = threadIdx.x % TPN;
    const int c0 = lane * 8;

    float acc[8];
    {
        uint4 u = *(const uint4*)(hs + (size_t)node * DOUT + c0);  // self loop
        const __half2* hp = (const __half2*)&u;
#pragma unroll
        for (int q = 0; q < 4; q++) {
            float2 f = __half22float2(hp[q]);
            acc[2 * q] = f.x;
            acc[2 * q + 1] = f.y;
        }
    }

    const int e0 = rowptr[node];
    const int e1 = rowptr[node + 1];
    int e = e0;
    for (; e + 4 <= e1; e += 4) {
        int s0 = ssrc[e + 0];
        int s1 = ssrc[e + 1];
        int s2 = ssrc[e + 2];
        int s3 = ssrc[e + 3];
        uint4 u0 = *(const uint4*)(hs + (size_t)s0 * DOUT + c0);
        uint4 u1 = *(const uint4*)(hs + (size_t)s1 * DOUT + c0);
        uint4 u2 = *(const uint4*)(hs + (size_t)s2 * DOUT + c0);
        uint4 u3 = *(const uint4*)(hs + (size_t)s3 * DOUT + c0);
        const __half2* p0 = (const __half2*)&u0;
        const __half2* p1 = (const __half2*)&u1;
        const __half2* p2 = (const __half2*)&u2;
        const __half2* p3 = (const __half2*)&u3;
#pragma unroll
        for (int q = 0; q < 4; q++) {
            float2 f0 = __half22float2(p0[q]);
            float2 f1 = __half22float2(p1[q]);
            float2 f2 = __half22float2(p2[q]);
            float2 f3 = __half22float2(p3[q]);
            acc[2 * q]     += (f0.x + f1.x) + (f2.x + f3.x);
            acc[2 * q + 1] += (f0.y + f1.y) + (f2.y + f3.y);
        }
    }
    for (; e < e1; e++) {
        int s = ssrc[e];
        uint4 u = *(const uint4*)(hs + (size_t)s * DOUT + c0);
        const __half2* hp = (const __half2*)&u;
#pragma unroll
        for (int q = 0; q < 4; q++) {
            float2 f = __half22float2(hp[q]);
            acc[2 * q] += f.x;
            acc[2 * q + 1] += f.y;
        }
    }

    const float di = dinv[node];
    float* op = out + (size_t)node * DOUT + c0;
#pragma unroll
    for (int q = 0; q < 2; q++) {
        float4 bq = *(const float4*)(bias + c0 + 4 * q);
        float4 o;
        o.x = di * acc[4 * q + 0] + bq.x;
        o.y = di * acc[4 * q + 1] + bq.y;
        o.z = di * acc[4 * q + 2] + bq.z;
        o.w = di * acc[4 * q + 3] + bq.w;
        if (RELU) {
            o.x = fmaxf(o.x, 0.f);
            o.y = fmaxf(o.y, 0.f);
            o.z = fmaxf(o.z, 0.f);
            o.w = fmaxf(o.w, 0.f);
        }
        *(float4*)(op + 4 * q) = o;
    }
}

// ---------------------------------------------------------------------------

extern "C" void kernel_launch(void* const* d_in, const int* in_sizes, int n_in,
                              void* d_out, int out_size, void* d_ws, size_t ws_size,
                              hipStream_t stream) {
    const float* x  = (const float*)d_in[0];
    const int*   ei = (const int*)d_in[1];
    const float* W1 = (const float*)d_in[3];
    const float* b1 = (const float*)d_in[4];
    const float* W2 = (const float*)d_in[5];
    const float* b2 = (const float*)d_in[6];
    float* out = (float*)d_out;

    const int N = in_sizes[0] / KDIM;  // 100000
    const int E = in_sizes[1] / 2;     // 1600000
    const int* esrc = ei;
    const int* edst = ei + E;
    const int NB = (N + BSIZE - 1) >> BSHIFT;  // 196

    char* ws = (char*)d_ws;
    size_t off = 0;
    auto alloc = [&](size_t bytes) {
        size_t p = off;
        off = (off + bytes + 511) & ~(size_t)511;
        return p;
    };
    int*    bhist   = (int*)(ws + alloc((size_t)NB * 4));
    int*    bbase   = (int*)(ws + alloc((size_t)(NB + 1) * 4));
    int*    bcursor = (int*)(ws + alloc((size_t)NB * 4));
    int*    rowptr  = (int*)(ws + alloc((size_t)(N + 1) * 4));
    float*  dinv    = (float*)(ws + alloc((size_t)N * 4));
    int*    ssrc    = (int*)(ws + alloc((size_t)E * 4));
    __half* hs      = (__half*)(ws + alloc((size_t)N * KDIM * 2));  // fp16 hs1/hs2
    float*  out1    = (float*)(ws + alloc((size_t)N * KDIM * 4));
    unsigned int* packed = (unsigned int*)hs;  // E*4 = 6.4MB < hs 25.6MB; consumed first
    (void)ws_size; (void)n_in; (void)out_size;

    const int eb = (E + ECHUNK - 1) / ECHUNK;

    hipMemsetAsync(bhist, 0, (size_t)NB * 4, stream);

    bcount_kernel<<<eb, 256, 0, stream>>>(edst, bhist, E, NB);
    bscan_kernel<<<1, 256, 0, stream>>>(bhist, bbase, bcursor, NB, E);
    bscatter_kernel<<<eb, 256, 0, stream>>>(esrc, edst, bcursor, packed, E, NB);
    bplace_kernel<<<NB, 256, 0, stream>>>(packed, bbase, rowptr, dinv, ssrc, N, E);

    // layer 1
    gemm_scale_kernel<128><<<(N + 127) / 128, 256, 0, stream>>>(x, W1, dinv, hs, N);
    agg_kernel<128, true><<<(N + 15) / 16, 256, 0, stream>>>(hs, rowptr, ssrc, dinv, b1, out1, N);

    // layer 2
    gemm_scale_kernel<64><<<(N + 127) / 128, 256, 0, stream>>>(out1, W2, dinv, hs, N);
    agg_kernel<64, false><<<(N + 31) / 32, 256, 0, stream>>>(hs, rowptr, ssrc, dinv, b2, out, N);
}

// Round 5
// 286.811 us; speedup vs baseline: 2.0209x; 1.2542x over previous
//
#include <hip/hip_runtime.h>
#include <hip/hip_fp16.h>

// ---------------------------------------------------------------------------
// GCN 2-layer forward on MI355X.
//   CSR build: 2-level bucket sort (bucket = dst>>9).
//   hs = fp16[(X @ W) * dinv]  via MFMA fp16 (W staged fp16 in LDS n-major,
//                              A-fragments straight from global, fp32 acc)
//   out[i] = act(dinv[i] * (sum_{j->i} hs[j] + hs[i]) + b)
//            (fp16 gather, fp32 accumulate; layer-1 output stored fp16 so
//             layer-2 MFMA A-frags load without conversion)
// ---------------------------------------------------------------------------

#define KDIM 128
#define BSHIFT 9
#define BSIZE 512
#define ECHUNK 8192
#define PACK_SHIFT 20
#define PACK_MASK ((1u << PACK_SHIFT) - 1)

typedef _Float16 h8 __attribute__((ext_vector_type(8)));
typedef float f4v __attribute__((ext_vector_type(4)));

// ---- bucket histogram -----------------------------------------------------

__global__ void bcount_kernel(const int* __restrict__ dst, int* __restrict__ bhist,
                              int E, int NB) {
    __shared__ int lcnt[256];
    const int t = threadIdx.x;
    lcnt[t] = 0;
    __syncthreads();
    const int base = blockIdx.x * ECHUNK;
#pragma unroll
    for (int j = 0; j < ECHUNK / 256; j++) {
        int e = base + j * 256 + t;
        if (e < E) atomicAdd(&lcnt[dst[e] >> BSHIFT], 1);
    }
    __syncthreads();
    if (t < NB && lcnt[t]) atomicAdd(&bhist[t], lcnt[t]);
}

__global__ void bscan_kernel(const int* __restrict__ bhist, int* __restrict__ bbase,
                             int* __restrict__ bcursor, int NB, int E) {
    __shared__ int tmp[256];
    const int t = threadIdx.x;
    tmp[t] = (t < NB) ? bhist[t] : 0;
    __syncthreads();
    for (int off = 1; off < 256; off <<= 1) {
        int x = (t >= off) ? tmp[t - off] : 0;
        __syncthreads();
        if (t >= off) tmp[t] += x;
        __syncthreads();
    }
    int exc = (t == 0) ? 0 : tmp[t - 1];
    if (t < NB) {
        bbase[t] = exc;
        bcursor[t] = exc;
    }
    if (t == 0) bbase[NB] = E;
}

// ---- radix-partition edges into bucket regions ----------------------------

__launch_bounds__(256) __global__
void bscatter_kernel(const int* __restrict__ src, const int* __restrict__ dst,
                     int* __restrict__ bcursor, unsigned int* __restrict__ packed_out,
                     int E, int NB) {
    __shared__ int lcnt[256];
    __shared__ int lexc[256];
    __shared__ int lbase[256];
    __shared__ unsigned int lpacked[ECHUNK];
    __shared__ unsigned char lbslot[ECHUNK];

    const int t = threadIdx.x;
    lcnt[t] = 0;
    __syncthreads();

    const int base = blockIdx.x * ECHUNK;
    const int cnt = min(ECHUNK, E - base);

#pragma unroll
    for (int j = 0; j < ECHUNK / 256; j++) {
        int e = base + j * 256 + t;
        if (e < E) atomicAdd(&lcnt[dst[e] >> BSHIFT], 1);
    }
    __syncthreads();

    lexc[t] = lcnt[t];
    __syncthreads();
    for (int off = 1; off < 256; off <<= 1) {
        int x = (t >= off) ? lexc[t - off] : 0;
        __syncthreads();
        if (t >= off) lexc[t] += x;
        __syncthreads();
    }
    int inc = lexc[t];
    __syncthreads();
    lexc[t] = inc - lcnt[t];

    if (t < NB && lcnt[t]) lbase[t] = atomicAdd(&bcursor[t], lcnt[t]);

    lcnt[t] = lexc[t];
    __syncthreads();

#pragma unroll
    for (int j = 0; j < ECHUNK / 256; j++) {
        int e = base + j * 256 + t;
        if (e < E) {
            int d = dst[e];
            int b = d >> BSHIFT;
            int pos = atomicAdd(&lcnt[b], 1);
            lpacked[pos] = (unsigned int)src[e] | ((unsigned int)(d & (BSIZE - 1)) << PACK_SHIFT);
            lbslot[pos] = (unsigned char)b;
        }
    }
    __syncthreads();

#pragma unroll
    for (int j = 0; j < ECHUNK / 256; j++) {
        int s = j * 256 + t;
        if (s < cnt) {
            int b = lbslot[s];
            packed_out[lbase[b] + (s - lexc[b])] = lpacked[s];
        }
    }
}

// ---- per-bucket fine placement + rowptr + dinv ----------------------------

__launch_bounds__(256) __global__
void bplace_kernel(const unsigned int* __restrict__ packed, const int* __restrict__ bbase,
                   int* __restrict__ rowptr, float* __restrict__ dinv,
                   int* __restrict__ ssrc, int N, int E) {
    __shared__ int ncnt[BSIZE];
    __shared__ int nexc[BSIZE];
    __shared__ int s1[256];

    const int t = threadIdx.x;
    const int b = blockIdx.x;
    ncnt[t] = 0;
    ncnt[t + 256] = 0;
    __syncthreads();

    const int e0 = bbase[b];
    const int e1 = bbase[b + 1];
    for (int e = e0 + t; e < e1; e += 256) {
        atomicAdd(&ncnt[packed[e] >> PACK_SHIFT], 1);
    }
    __syncthreads();

    const int a0 = ncnt[2 * t];
    const int a1 = ncnt[2 * t + 1];
    s1[t] = a0 + a1;
    __syncthreads();
    for (int off = 1; off < 256; off <<= 1) {
        int x = (t >= off) ? s1[t - off] : 0;
        __syncthreads();
        if (t >= off) s1[t] += x;
        __syncthreads();
    }
    const int base2 = (t == 0) ? 0 : s1[t - 1];
    nexc[2 * t] = base2;
    nexc[2 * t + 1] = base2 + a0;

    const int nodebase = b * BSIZE;
    const int n0 = nodebase + 2 * t;
    const int n1 = n0 + 1;
    if (n0 < N) {
        rowptr[n0] = e0 + base2;
        dinv[n0] = rsqrtf((float)(a0 + 1));
    }
    if (n1 < N) {
        rowptr[n1] = e0 + base2 + a0;
        dinv[n1] = rsqrtf((float)(a1 + 1));
    }
    if (b == 0 && t == 0) rowptr[N] = E;
    __syncthreads();

    for (int e = e0 + t; e < e1; e += 256) {
        unsigned int p = packed[e];
        int d = p >> PACK_SHIFT;
        int pos = e0 + atomicAdd(&nexc[d], 1);
        ssrc[pos] = (int)(p & PACK_MASK);
    }
}

// ---- MFMA GEMM + per-row scale, fp16 output -------------------------------
// outh[r,:] = fp16( (A[r,:] @ W) * dinv[r] ),  A: [N,128] fp32 or fp16.
// Block 256 thr = 4 waves; wave covers 32 rows (2x 16-row tiles) x DOUT.
// W staged fp16 in LDS n-major (pad stride 136 halves) -> b128 frag reads.
// Verified layouts (learn_hip m89/m91): A-frag m=lane&15,k=quad*8+j;
// B-frag n=lane&15; C/D col=lane&15,row=quad*4+reg.

__device__ inline h8 pack8(float4 u, float4 v) {
    h8 r;
    r[0] = (_Float16)u.x; r[1] = (_Float16)u.y; r[2] = (_Float16)u.z; r[3] = (_Float16)u.w;
    r[4] = (_Float16)v.x; r[5] = (_Float16)v.y; r[6] = (_Float16)v.z; r[7] = (_Float16)v.w;
    return r;
}

template <int DOUT, bool AHALF>
__launch_bounds__(256) __global__
void gemm_mfma_kernel(const void* __restrict__ Xv, const float* __restrict__ W,
                      const float* __restrict__ dinv, _Float16* __restrict__ outh, int N) {
    constexpr int K = KDIM;       // 128
    constexpr int KS = K + 8;     // 136 halves: 16B-aligned pad stride
    constexpr int NT = DOUT / 16; // col tiles
    __shared__ _Float16 Wl[DOUT * KS];

    const int t = threadIdx.x;
    const int wave = t >> 6;
    const int lane = t & 63;
    const int l15 = lane & 15;
    const int quad = lane >> 4;

    // stage W (fp32 [K][DOUT] row-major) -> Wl fp16 n-major [n][k]
#pragma unroll
    for (int i = t; i < DOUT * (K / 4); i += 256) {
        int n = i & (DOUT - 1);
        int kg = i / DOUT;       // 0..31, covers k = 4*kg..+3
        union { _Float16 h[4]; uint2 u; } tmp;
#pragma unroll
        for (int j = 0; j < 4; j++)
            tmp.h[j] = (_Float16)W[(size_t)(kg * 4 + j) * DOUT + n];
        *(uint2*)(&Wl[n * KS + kg * 4]) = tmp.u;
    }
    __syncthreads();

    const int rowbase = blockIdx.x * 128;
    const int row0 = rowbase + wave * 32 + l15;
    const int row1 = row0 + 16;
    const int rc0 = min(row0, N - 1);   // clamp: OOB A rows only feed OOB D rows
    const int rc1 = min(row1, N - 1);

    f4v acc[2][NT];
#pragma unroll
    for (int r = 0; r < 2; r++)
#pragma unroll
        for (int ct = 0; ct < NT; ct++) acc[r][ct] = (f4v)0.0f;

#pragma unroll
    for (int kc = 0; kc < K; kc += 32) {
        const int kof = kc + quad * 8;
        h8 a0, a1;
        if (AHALF) {
            const _Float16* Xh = (const _Float16*)Xv;
            a0 = *(const h8*)(Xh + (size_t)rc0 * K + kof);
            a1 = *(const h8*)(Xh + (size_t)rc1 * K + kof);
        } else {
            const float* Xf = (const float*)Xv;
            const float* p0 = Xf + (size_t)rc0 * K + kof;
            const float* p1 = Xf + (size_t)rc1 * K + kof;
            a0 = pack8(*(const float4*)p0, *(const float4*)(p0 + 4));
            a1 = pack8(*(const float4*)p1, *(const float4*)(p1 + 4));
        }
#pragma unroll
        for (int ct = 0; ct < NT; ct++) {
            h8 b = *(const h8*)(&Wl[(size_t)(ct * 16 + l15) * KS + kof]);
            acc[0][ct] = __builtin_amdgcn_mfma_f32_16x16x32_f16(a0, b, acc[0][ct], 0, 0, 0);
            acc[1][ct] = __builtin_amdgcn_mfma_f32_16x16x32_f16(a1, b, acc[1][ct], 0, 0, 0);
        }
    }

#pragma unroll
    for (int r = 0; r < 2; r++) {
        const int rb = rowbase + wave * 32 + r * 16 + quad * 4;
#pragma unroll
        for (int g = 0; g < 4; g++) {
            int row = rb + g;
            if (row < N) {
                float di = dinv[row];
                _Float16* op = outh + (size_t)row * DOUT + l15;
#pragma unroll
                for (int ct = 0; ct < NT; ct++)
                    op[ct * 16] = (_Float16)(acc[r][ct][g] * di);
            }
        }
    }
}

// ---- Aggregation: out[i] = act(dinv[i]*(sum_e hs[src[e]] + hs[i]) + b) ----
// hs fp16; TPN = DOUT/8 lanes/node, 16B per lane; fp32 accumulate; unroll-4.
// HOUT: write fp16 (layer-1 activation) or fp32 (final output).

template <int DOUT, bool RELU, bool HOUT>
__launch_bounds__(256) __global__
void agg_kernel(const __half* __restrict__ hs, const int* __restrict__ rowptr,
                const int* __restrict__ ssrc, const float* __restrict__ dinv,
                const float* __restrict__ bias, void* __restrict__ outv, int N) {
    constexpr int TPN = DOUT / 8;
    const int npb = blockDim.x / TPN;
    const int node = blockIdx.x * npb + threadIdx.x / TPN;
    if (node >= N) return;
    const int lane = threadIdx.x % TPN;
    const int c0 = lane * 8;

    float acc[8];
    {
        uint4 u = *(const uint4*)(hs + (size_t)node * DOUT + c0);  // self loop
        const __half2* hp = (const __half2*)&u;
#pragma unroll
        for (int q = 0; q < 4; q++) {
            float2 f = __half22float2(hp[q]);
            acc[2 * q] = f.x;
            acc[2 * q + 1] = f.y;
        }
    }

    const int e0 = rowptr[node];
    const int e1 = rowptr[node + 1];
    int e = e0;
    for (; e + 4 <= e1; e += 4) {
        int s0 = ssrc[e + 0];
        int s1 = ssrc[e + 1];
        int s2 = ssrc[e + 2];
        int s3 = ssrc[e + 3];
        uint4 u0 = *(const uint4*)(hs + (size_t)s0 * DOUT + c0);
        uint4 u1 = *(const uint4*)(hs + (size_t)s1 * DOUT + c0);
        uint4 u2 = *(const uint4*)(hs + (size_t)s2 * DOUT + c0);
        uint4 u3 = *(const uint4*)(hs + (size_t)s3 * DOUT + c0);
        const __half2* p0 = (const __half2*)&u0;
        const __half2* p1 = (const __half2*)&u1;
        const __half2* p2 = (const __half2*)&u2;
        const __half2* p3 = (const __half2*)&u3;
#pragma unroll
        for (int q = 0; q < 4; q++) {
            float2 f0 = __half22float2(p0[q]);
            float2 f1 = __half22float2(p1[q]);
            float2 f2 = __half22float2(p2[q]);
            float2 f3 = __half22float2(p3[q]);
            acc[2 * q]     += (f0.x + f1.x) + (f2.x + f3.x);
            acc[2 * q + 1] += (f0.y + f1.y) + (f2.y + f3.y);
        }
    }
    for (; e < e1; e++) {
        int s = ssrc[e];
        uint4 u = *(const uint4*)(hs + (size_t)s * DOUT + c0);
        const __half2* hp = (const __half2*)&u;
#pragma unroll
        for (int q = 0; q < 4; q++) {
            float2 f = __half22float2(hp[q]);
            acc[2 * q] += f.x;
            acc[2 * q + 1] += f.y;
        }
    }

    const float di = dinv[node];
    float o[8];
#pragma unroll
    for (int q = 0; q < 2; q++) {
        float4 bq = *(const float4*)(bias + c0 + 4 * q);
        o[4 * q + 0] = di * acc[4 * q + 0] + bq.x;
        o[4 * q + 1] = di * acc[4 * q + 1] + bq.y;
        o[4 * q + 2] = di * acc[4 * q + 2] + bq.z;
        o[4 * q + 3] = di * acc[4 * q + 3] + bq.w;
    }
    if (RELU) {
#pragma unroll
        for (int j = 0; j < 8; j++) o[j] = fmaxf(o[j], 0.f);
    }
    if (HOUT) {
        union { __half2 h[4]; uint4 u; } pk;
#pragma unroll
        for (int q = 0; q < 4; q++)
            pk.h[q] = __floats2half2_rn(o[2 * q], o[2 * q + 1]);
        *(uint4*)((__half*)outv + (size_t)node * DOUT + c0) = pk.u;
    } else {
        float* op = (float*)outv + (size_t)node * DOUT + c0;
        *(float4*)op = make_float4(o[0], o[1], o[2], o[3]);
        *(float4*)(op + 4) = make_float4(o[4], o[5], o[6], o[7]);
    }
}

// ---------------------------------------------------------------------------

extern "C" void kernel_launch(void* const* d_in, const int* in_sizes, int n_in,
                              void* d_out, int out_size, void* d_ws, size_t ws_size,
                              hipStream_t stream) {
    const float* x  = (const float*)d_in[0];
    const int*   ei = (const int*)d_in[1];
    const float* W1 = (const float*)d_in[3];
    const float* b1 = (const float*)d_in[4];
    const float* W2 = (const float*)d_in[5];
    const float* b2 = (const float*)d_in[6];
    float* out = (float*)d_out;

    const int N = in_sizes[0] / KDIM;  // 100000
    const int E = in_sizes[1] / 2;     // 1600000
    const int* esrc = ei;
    const int* edst = ei + E;
    const int NB = (N + BSIZE - 1) >> BSHIFT;  // 196

    char* ws = (char*)d_ws;
    size_t off = 0;
    auto alloc = [&](size_t bytes) {
        size_t p = off;
        off = (off + bytes + 511) & ~(size_t)511;
        return p;
    };
    int*      bhist   = (int*)(ws + alloc((size_t)NB * 4));
    int*      bbase   = (int*)(ws + alloc((size_t)(NB + 1) * 4));
    int*      bcursor = (int*)(ws + alloc((size_t)NB * 4));
    int*      rowptr  = (int*)(ws + alloc((size_t)(N + 1) * 4));
    float*    dinv    = (float*)(ws + alloc((size_t)N * 4));
    int*      ssrc    = (int*)(ws + alloc((size_t)E * 4));
    _Float16* hs      = (_Float16*)(ws + alloc((size_t)N * KDIM * 2));  // fp16 hs
    _Float16* out1    = (_Float16*)(ws + alloc((size_t)N * KDIM * 2));  // fp16 act
    unsigned int* packed = (unsigned int*)hs;  // E*4 = 6.4MB < 25.6MB; consumed first
    (void)ws_size; (void)n_in; (void)out_size;

    const int eb = (E + ECHUNK - 1) / ECHUNK;

    hipMemsetAsync(bhist, 0, (size_t)NB * 4, stream);

    bcount_kernel<<<eb, 256, 0, stream>>>(edst, bhist, E, NB);
    bscan_kernel<<<1, 256, 0, stream>>>(bhist, bbase, bcursor, NB, E);
    bscatter_kernel<<<eb, 256, 0, stream>>>(esrc, edst, bcursor, packed, E, NB);
    bplace_kernel<<<NB, 256, 0, stream>>>(packed, bbase, rowptr, dinv, ssrc, N, E);

    // layer 1: hs = fp16[(x @ W1)*dinv]; out1 = fp16[relu(dinv*(gather+self)+b1)]
    gemm_mfma_kernel<128, false><<<(N + 127) / 128, 256, 0, stream>>>(x, W1, dinv, hs, N);
    agg_kernel<128, true, true><<<(N + 15) / 16, 256, 0, stream>>>(
        (const __half*)hs, rowptr, ssrc, dinv, b1, out1, N);

    // layer 2: hs = fp16[(out1 @ W2)*dinv]; out = dinv*(gather+self) + b2
    gemm_mfma_kernel<64, true><<<(N + 127) / 128, 256, 0, stream>>>(out1, W2, dinv, hs, N);
    agg_kernel<64, false, false><<<(N + 31) / 32, 256, 0, stream>>>(
        (const __half*)hs, rowptr, ssrc, dinv, b2, out, N);
}